// Round 2
// baseline (210.471 us; speedup 1.0000x reference)
//
#include <hip/hip_runtime.h>
#include <hip/hip_cooperative_groups.h>
#include <math.h>

namespace cg = cooperative_groups;

#define HW     16384
#define CDIM   10
#define NPIX   131072        // B*H*W
#define NPLANE 1310720       // B*C*H*W
#define BN_N   131072.0f
#define EPS_BN 1e-5f
#define NBLK   256
#define NTHR   512

__device__ __forceinline__ float sigf(float x) { return 1.0f / (1.0f + __expf(-x)); }
__device__ __forceinline__ float tanh_fast(float x) {
    x = fminf(fmaxf(x, -15.0f), 15.0f);
    float e = __expf(2.0f * x);
    return (e - 1.0f) / (e + 1.0f);
}

// DPP-based 64-lane sum: VALU-only, no LDS pipe. Result valid in lane 63.
template<int CTRL>
__device__ __forceinline__ float dpp_add(float x) {
    int t = __builtin_amdgcn_update_dpp(0, __float_as_int(x), CTRL, 0xF, 0xF, true);
    return x + __int_as_float(t);
}
__device__ __forceinline__ float wred63(float x) {
    x = dpp_add<0x111>(x);   // row_shr:1
    x = dpp_add<0x112>(x);   // row_shr:2
    x = dpp_add<0x114>(x);   // row_shr:4
    x = dpp_add<0x118>(x);   // row_shr:8  -> lane 15 of each row has row sum
    x = dpp_add<0x142>(x);   // row_bcast:15
    x = dpp_add<0x143>(x);   // row_bcast:31 -> lane 63 = sum(0..63)
    return x;
}

// One cooperative kernel: phase1 (node0, att, y1 stats) -> grid.sync ->
// phase2 (BN1 finalize, x2, y2 stats) -> grid.sync -> phase3 (BN2, GRU1).
// All per-pixel intermediates stay in registers across the grid syncs.
// Weights read from global with compile-time-uniform indices -> s_load/SGPR.
__global__ __launch_bounds__(NTHR, 2) void fused(
    const float* __restrict__ f0, const float* __restrict__ f1,
    const float* __restrict__ h0, const float* __restrict__ h1, const float* __restrict__ h2,
    const float* __restrict__ W_att, const float* __restrict__ b_att,
    const float* __restrict__ W_r1, const float* __restrict__ g_r1, const float* __restrict__ be_r1,
    const float* __restrict__ W_r2, const float* __restrict__ g_r2, const float* __restrict__ be_r2,
    const float* __restrict__ Wg0, const float* __restrict__ bg0, const float* __restrict__ Wc0,
    const float* __restrict__ Wg1, const float* __restrict__ bg1, const float* __restrict__ Wc1,
    float* __restrict__ node0, float* __restrict__ node1, float* __restrict__ att_out,
    float* __restrict__ part1, float* __restrict__ part2)
{
    cg::grid_group grid = cg::this_grid();
    __shared__ float sPart[8 * 40];   // per-wave partials
    __shared__ float sRed[40];        // block-level reduced stats
    const int tid = threadIdx.x;
    const int bid = blockIdx.x;
    const int p = bid * NTHR + tid;
    const int b = p >> 14, s = p & 16383;
    const int base = b * (CDIM * HW) + s;
    const int wave = tid >> 6, lane = tid & 63;

    // ---------------- phase 1 ----------------
    float vh1[10], vh2[10], vf1[10], vf0[10], vh0[10];
#pragma unroll
    for (int c = 0; c < 10; c++) {
        vh1[c] = h1[base + c * HW];
        vh2[c] = h2[base + c * HW];
        vf1[c] = f1[base + c * HW];
        vf0[c] = f0[base + c * HW];
        vh0[c] = h0[base + c * HW];
    }

    // node0 = GRU0(x=h0, h=f0)
    {
        float g0 = bg0[0], g1 = bg0[1];
#pragma unroll
        for (int i = 0; i < 10; i++) {
            g0 = fmaf(Wg0[i],      vh0[i], fmaf(Wg0[10 + i], vf0[i], g0));
            g1 = fmaf(Wg0[20 + i], vh0[i], fmaf(Wg0[30 + i], vf0[i], g1));
        }
        const float r = sigf(g0), u = sigf(g1);
#pragma unroll
        for (int o = 0; o < 10; o++) {
            float acc = 0.0f;
#pragma unroll
            for (int i = 0; i < 10; i++) acc = fmaf(Wc0[o * 20 + i], vh0[i], acc);
#pragma unroll
            for (int i = 0; i < 10; i++) acc = fmaf(Wc0[o * 20 + 10 + i], r * vf0[i], acc);
            node0[base + o * HW] = (1.0f - u) * vf0[o] + u * tanh_fast(acc);
        }
    }

    // comp_att
    float z = b_att[0];
#pragma unroll
    for (int c = 0; c < 10; c++) z = fmaf(W_att[c], vh1[c], fmaf(W_att[10 + c], vh2[c], z));
    const float att = sigf(z);
    att_out[p] = att;

    // x = [f1, (h1+h2)*att]; acc1 = W_r1 @ x ; BN1 partial stats via DPP
    float x[20];
#pragma unroll
    for (int c = 0; c < 10; c++) { x[c] = vf1[c]; x[10 + c] = (vh1[c] + vh2[c]) * att; }
    float acc1[20];
#pragma unroll
    for (int o = 0; o < 20; o++) {
        float acc = 0.0f;
#pragma unroll
        for (int i = 0; i < 20; i++) acc = fmaf(W_r1[o * 20 + i], x[i], acc);
        acc1[o] = acc;
        float rs = wred63(acc);
        float rq = wred63(acc * acc);
        if (lane == 63) { sPart[wave * 40 + o] = rs; sPart[wave * 40 + 20 + o] = rq; }
    }
    __syncthreads();
    if (tid < 40) {
        float t = 0.0f;
#pragma unroll
        for (int w = 0; w < 8; w++) t += sPart[w * 40 + tid];
        part1[tid * NBLK + bid] = t;   // layout [40][NBLK]
    }
    grid.sync();

    // ---------------- phase 2 ----------------
    // redundant per-block reduction of part1 (40 x 256 floats, L2/L3-resident)
    for (int ch = wave; ch < 40; ch += 8) {
        float v = part1[ch * NBLK + lane]       + part1[ch * NBLK + lane + 64]
                + part1[ch * NBLK + lane + 128] + part1[ch * NBLK + lane + 192];
        v = wred63(v);
        if (lane == 63) sRed[ch] = v;
    }
    __syncthreads();
    float A1[20], B1[20];
#pragma unroll
    for (int c = 0; c < 20; c++) {
        float mean = sRed[c] * (1.0f / BN_N);
        float var  = sRed[20 + c] * (1.0f / BN_N) - mean * mean;
        float a = g_r1[c] * rsqrtf(var + EPS_BN);
        A1[c] = a;
        B1[c] = be_r1[c] - mean * a;
    }
    float x2[20];
#pragma unroll
    for (int o = 0; o < 20; o++) x2[o] = fmaxf(fmaf(A1[o], acc1[o], B1[o]), 0.0f);

    float acc2[10];
#pragma unroll
    for (int o = 0; o < 10; o++) {
        float acc = 0.0f;
#pragma unroll
        for (int i = 0; i < 20; i++) acc = fmaf(W_r2[o * 20 + i], x2[i], acc);
        acc2[o] = acc;
        float rs = wred63(acc);
        float rq = wred63(acc * acc);
        if (lane == 63) { sPart[wave * 20 + o] = rs; sPart[wave * 20 + 10 + o] = rq; }
    }
    __syncthreads();
    if (tid < 20) {
        float t = 0.0f;
#pragma unroll
        for (int w = 0; w < 8; w++) t += sPart[w * 20 + tid];
        part2[tid * NBLK + bid] = t;   // layout [20][NBLK]
    }
    grid.sync();

    // ---------------- phase 3 ----------------
    for (int ch = wave; ch < 20; ch += 8) {
        float v = part2[ch * NBLK + lane]       + part2[ch * NBLK + lane + 64]
                + part2[ch * NBLK + lane + 128] + part2[ch * NBLK + lane + 192];
        v = wred63(v);
        if (lane == 63) sRed[ch] = v;
    }
    __syncthreads();
    float comp[10];
#pragma unroll
    for (int c = 0; c < 10; c++) {
        float mean = sRed[c] * (1.0f / BN_N);
        float var  = sRed[10 + c] * (1.0f / BN_N) - mean * mean;
        float a = g_r2[c] * rsqrtf(var + EPS_BN);
        comp[c] = fmaxf(fmaf(a, acc2[c], be_r2[c] - mean * a), 0.0f);
    }
    float g0 = bg1[0], g1v = bg1[1];
#pragma unroll
    for (int i = 0; i < 10; i++) {
        g0  = fmaf(Wg1[i],      comp[i], fmaf(Wg1[10 + i], vf1[i], g0));
        g1v = fmaf(Wg1[20 + i], comp[i], fmaf(Wg1[30 + i], vf1[i], g1v));
    }
    const float r = sigf(g0), u = sigf(g1v);
#pragma unroll
    for (int o = 0; o < 10; o++) {
        float acc = 0.0f;
#pragma unroll
        for (int i = 0; i < 10; i++) acc = fmaf(Wc1[o * 20 + i], comp[i], acc);
#pragma unroll
        for (int i = 0; i < 10; i++) acc = fmaf(Wc1[o * 20 + 10 + i], r * vf1[i], acc);
        node1[base + o * HW] = (1.0f - u) * vf1[o] + u * tanh_fast(acc);
    }
}

extern "C" void kernel_launch(void* const* d_in, const int* in_sizes, int n_in,
                              void* d_out, int out_size, void* d_ws, size_t ws_size,
                              hipStream_t stream) {
    const float* f0    = (const float*)d_in[0];
    const float* f1    = (const float*)d_in[1];
    const float* h0    = (const float*)d_in[2];
    const float* h1    = (const float*)d_in[3];
    const float* h2    = (const float*)d_in[4];
    const float* W_att = (const float*)d_in[5];
    const float* b_att = (const float*)d_in[6];
    const float* W_r1  = (const float*)d_in[7];
    const float* g_r1  = (const float*)d_in[8];
    const float* be_r1 = (const float*)d_in[9];
    const float* W_r2  = (const float*)d_in[10];
    const float* g_r2  = (const float*)d_in[11];
    const float* be_r2 = (const float*)d_in[12];
    const float* Wg0   = (const float*)d_in[13];
    const float* bg0   = (const float*)d_in[14];
    const float* Wc0   = (const float*)d_in[15];
    const float* Wg1   = (const float*)d_in[16];
    const float* bg1   = (const float*)d_in[17];
    const float* Wc1   = (const float*)d_in[18];

    float* out   = (float*)d_out;
    float* node0 = out;
    float* node1 = out + NPLANE;
    float* attO  = out + 2 * NPLANE;

    float* part1 = (float*)d_ws;          // 40*NBLK floats
    float* part2 = part1 + 40 * NBLK;     // 20*NBLK floats

    void* args[] = {
        (void*)&f0, (void*)&f1, (void*)&h0, (void*)&h1, (void*)&h2,
        (void*)&W_att, (void*)&b_att,
        (void*)&W_r1, (void*)&g_r1, (void*)&be_r1,
        (void*)&W_r2, (void*)&g_r2, (void*)&be_r2,
        (void*)&Wg0, (void*)&bg0, (void*)&Wc0,
        (void*)&Wg1, (void*)&bg1, (void*)&Wc1,
        (void*)&node0, (void*)&node1, (void*)&attO,
        (void*)&part1, (void*)&part2
    };
    hipLaunchCooperativeKernel((const void*)fused, dim3(NBLK), dim3(NTHR),
                               args, 0, stream);
}

// Round 3
// 180.820 us; speedup vs baseline: 1.1640x; 1.1640x over previous
//
#include <hip/hip_runtime.h>
#include <math.h>

#define HW     16384
#define CDIM   10
#define NPIX   131072        // B*H*W
#define NPLANE 1310720       // B*C*H*W
#define BN_N   131072.0f
#define EPS_BN 1e-5f
#define NB1    512           // K1 blocks (256 thr each)
#define NB2    256           // K2K3 blocks (512 thr each)

__device__ __forceinline__ float sigf(float x) { return 1.0f / (1.0f + __expf(-x)); }
__device__ __forceinline__ float tanh_fast(float x) {
    x = fminf(fmaxf(x, -15.0f), 15.0f);
    float e = __expf(2.0f * x);
    return (e - 1.0f) / (e + 1.0f);
}

// DPP-based 64-lane sum: VALU-only. Result valid in lane 63.
template<int CTRL>
__device__ __forceinline__ float dpp_add(float x) {
    int t = __builtin_amdgcn_update_dpp(0, __float_as_int(x), CTRL, 0xF, 0xF, true);
    return x + __int_as_float(t);
}
__device__ __forceinline__ float wred63(float x) {
    x = dpp_add<0x111>(x);   // row_shr:1
    x = dpp_add<0x112>(x);   // row_shr:2
    x = dpp_add<0x114>(x);   // row_shr:4
    x = dpp_add<0x118>(x);   // row_shr:8
    x = dpp_add<0x142>(x);   // row_bcast:15
    x = dpp_add<0x143>(x);   // row_bcast:31 -> lane 63 = sum(0..63)
    return x;
}

// K1: node0 (GRU0), comp_att, BN1 partial stats -> part1[40][NB1] (plain stores;
// cross-kernel visibility is guaranteed by kernel-boundary release/acquire).
// Also zeroes the K2K3 barrier gate (K2K3 only runs after K1 completes).
__global__ __launch_bounds__(256) void kernA(
    const float* __restrict__ f0, const float* __restrict__ f1,
    const float* __restrict__ h0, const float* __restrict__ h1, const float* __restrict__ h2,
    const float* __restrict__ W_att, const float* __restrict__ b_att,
    const float* __restrict__ W_r1,
    const float* __restrict__ Wg0, const float* __restrict__ bg0, const float* __restrict__ Wc0,
    float* __restrict__ node0, float* __restrict__ att_out,
    float* __restrict__ part1, int* __restrict__ gate)
{
    __shared__ float sPart[4 * 40];
    const int tid = threadIdx.x;
    const int bid = blockIdx.x;
    if (bid == 0 && tid == 0) *gate = 0;
    const int p = bid * 256 + tid;
    const int b = p >> 14, s = p & 16383;
    const int base = b * (CDIM * HW) + s;
    const int wave = tid >> 6, lane = tid & 63;

    float vh1[10], vh2[10], vf1[10], vf0[10], vh0[10];
#pragma unroll
    for (int c = 0; c < 10; c++) {
        vh1[c] = h1[base + c * HW];
        vh2[c] = h2[base + c * HW];
        vf1[c] = f1[base + c * HW];
        vf0[c] = f0[base + c * HW];
        vh0[c] = h0[base + c * HW];
    }

    // node0 = GRU0(x=h0, h=f0)
    {
        float g0 = bg0[0], g1 = bg0[1];
#pragma unroll
        for (int i = 0; i < 10; i++) {
            g0 = fmaf(Wg0[i],      vh0[i], fmaf(Wg0[10 + i], vf0[i], g0));
            g1 = fmaf(Wg0[20 + i], vh0[i], fmaf(Wg0[30 + i], vf0[i], g1));
        }
        const float r = sigf(g0), u = sigf(g1);
#pragma unroll
        for (int o = 0; o < 10; o++) {
            float acc = 0.0f;
#pragma unroll
            for (int i = 0; i < 10; i++) acc = fmaf(Wc0[o * 20 + i], vh0[i], acc);
#pragma unroll
            for (int i = 0; i < 10; i++) acc = fmaf(Wc0[o * 20 + 10 + i], r * vf0[i], acc);
            node0[base + o * HW] = (1.0f - u) * vf0[o] + u * tanh_fast(acc);
        }
    }

    // comp_att
    float z = b_att[0];
#pragma unroll
    for (int c = 0; c < 10; c++) z = fmaf(W_att[c], vh1[c], fmaf(W_att[10 + c], vh2[c], z));
    const float att = sigf(z);
    att_out[p] = att;

    // x = [f1, (h1+h2)*att]; y1 = W_r1 @ x (stats only)
    float x[20];
#pragma unroll
    for (int c = 0; c < 10; c++) { x[c] = vf1[c]; x[10 + c] = (vh1[c] + vh2[c]) * att; }
#pragma unroll
    for (int o = 0; o < 20; o++) {
        float acc = 0.0f;
#pragma unroll
        for (int i = 0; i < 20; i++) acc = fmaf(W_r1[o * 20 + i], x[i], acc);
        float rs = wred63(acc);
        float rq = wred63(acc * acc);
        if (lane == 63) { sPart[wave * 40 + o] = rs; sPart[wave * 40 + 20 + o] = rq; }
    }
    __syncthreads();
    if (tid < 40) {
        float t = sPart[tid] + sPart[40 + tid] + sPart[80 + tid] + sPart[120 + tid];
        part1[tid * NB1 + bid] = t;   // layout [40][NB1]
    }
}

// K2K3: BN1 finalize + x2 + acc2 (in regs) | manual coherent-atomic grid barrier |
// BN2 finalize + GRU1. Cooperative launch guarantees co-residency for the barrier;
// the barrier itself uses only agent-scope atomics (no L2 writeback/invalidate).
__global__ __launch_bounds__(512) void kernBC(
    const float* __restrict__ f1, const float* __restrict__ h1, const float* __restrict__ h2,
    const float* __restrict__ W_att, const float* __restrict__ b_att,
    const float* __restrict__ W_r1, const float* __restrict__ g_r1, const float* __restrict__ be_r1,
    const float* __restrict__ W_r2, const float* __restrict__ g_r2, const float* __restrict__ be_r2,
    const float* __restrict__ Wg1, const float* __restrict__ bg1, const float* __restrict__ Wc1,
    const float* __restrict__ part1, float* __restrict__ part2, int* __restrict__ gate,
    float* __restrict__ node1)
{
    __shared__ float sPart[8 * 20];
    __shared__ float sRed[40];
    const int tid = threadIdx.x;
    const int bid = blockIdx.x;
    const int p = bid * 512 + tid;
    const int b = p >> 14, s = p & 16383;
    const int base = b * (CDIM * HW) + s;
    const int wave = tid >> 6, lane = tid & 63;

    // Redundant per-block reduction of part1 (plain loads; written by K1).
    for (int ch = wave; ch < 40; ch += 8) {
        float v = 0.0f;
#pragma unroll
        for (int k = 0; k < 8; k++) v += part1[ch * NB1 + k * 64 + lane];
        v = wred63(v);
        if (lane == 63) sRed[ch] = v;
    }
    __syncthreads();
    float A1[20], B1[20];
#pragma unroll
    for (int c = 0; c < 20; c++) {
        float mean = sRed[c] * (1.0f / BN_N);
        float var  = sRed[20 + c] * (1.0f / BN_N) - mean * mean;
        float a = g_r1[c] * rsqrtf(var + EPS_BN);
        A1[c] = a;
        B1[c] = be_r1[c] - mean * a;
    }

    float vh1[10], vh2[10], vf1[10];
#pragma unroll
    for (int c = 0; c < 10; c++) {
        vh1[c] = h1[base + c * HW];
        vh2[c] = h2[base + c * HW];
        vf1[c] = f1[base + c * HW];
    }
    float z = b_att[0];
#pragma unroll
    for (int c = 0; c < 10; c++) z = fmaf(W_att[c], vh1[c], fmaf(W_att[10 + c], vh2[c], z));
    const float att = sigf(z);

    float x[20];
#pragma unroll
    for (int c = 0; c < 10; c++) { x[c] = vf1[c]; x[10 + c] = (vh1[c] + vh2[c]) * att; }
    float x2[20];
#pragma unroll
    for (int o = 0; o < 20; o++) {
        float acc = 0.0f;
#pragma unroll
        for (int i = 0; i < 20; i++) acc = fmaf(W_r1[o * 20 + i], x[i], acc);
        x2[o] = fmaxf(fmaf(A1[o], acc, B1[o]), 0.0f);
    }
    float acc2[10];
#pragma unroll
    for (int o = 0; o < 10; o++) {
        float acc = 0.0f;
#pragma unroll
        for (int i = 0; i < 20; i++) acc = fmaf(W_r2[o * 20 + i], x2[i], acc);
        acc2[o] = acc;
        float rs = wred63(acc);
        float rq = wred63(acc * acc);
        if (lane == 63) { sPart[wave * 20 + o] = rs; sPart[wave * 20 + 10 + o] = rq; }
    }
    __syncthreads();
    if (tid < 20) {
        float t = 0.0f;
#pragma unroll
        for (int w = 0; w < 8; w++) t += sPart[w * 20 + tid];
        // agent-scope (coherent) store: visible at L3 coherence point, no cache flush
        __hip_atomic_store(&part2[tid * NB2 + bid], t, __ATOMIC_RELAXED, __HIP_MEMORY_SCOPE_AGENT);
    }
    __syncthreads();   // drains vmcnt: all waves' coherent stores complete

    // ---- manual grid barrier (coherent atomics only) ----
    if (tid == 0) {
        __hip_atomic_fetch_add(gate, 1, __ATOMIC_RELEASE, __HIP_MEMORY_SCOPE_AGENT);
        while (__hip_atomic_load(gate, __ATOMIC_RELAXED, __HIP_MEMORY_SCOPE_AGENT) < NB2)
            __builtin_amdgcn_s_sleep(2);
        (void)__hip_atomic_load(gate, __ATOMIC_ACQUIRE, __HIP_MEMORY_SCOPE_AGENT);
    }
    __syncthreads();

    // Redundant per-block reduction of part2 via coherent loads.
    for (int ch = wave; ch < 20; ch += 8) {
        float v = 0.0f;
#pragma unroll
        for (int k = 0; k < 4; k++)
            v += __hip_atomic_load(&part2[ch * NB2 + k * 64 + lane], __ATOMIC_RELAXED, __HIP_MEMORY_SCOPE_AGENT);
        v = wred63(v);
        if (lane == 63) sRed[ch] = v;
    }
    __syncthreads();

    float comp[10];
#pragma unroll
    for (int c = 0; c < 10; c++) {
        float mean = sRed[c] * (1.0f / BN_N);
        float var  = sRed[10 + c] * (1.0f / BN_N) - mean * mean;
        float a = g_r2[c] * rsqrtf(var + EPS_BN);
        comp[c] = fmaxf(fmaf(a, acc2[c], be_r2[c] - mean * a), 0.0f);
    }
    float g0 = bg1[0], g1v = bg1[1];
#pragma unroll
    for (int i = 0; i < 10; i++) {
        g0  = fmaf(Wg1[i],      comp[i], fmaf(Wg1[10 + i], vf1[i], g0));
        g1v = fmaf(Wg1[20 + i], comp[i], fmaf(Wg1[30 + i], vf1[i], g1v));
    }
    const float r = sigf(g0), u = sigf(g1v);
#pragma unroll
    for (int o = 0; o < 10; o++) {
        float acc = 0.0f;
#pragma unroll
        for (int i = 0; i < 10; i++) acc = fmaf(Wc1[o * 20 + i], comp[i], acc);
#pragma unroll
        for (int i = 0; i < 10; i++) acc = fmaf(Wc1[o * 20 + 10 + i], r * vf1[i], acc);
        node1[base + o * HW] = (1.0f - u) * vf1[o] + u * tanh_fast(acc);
    }
}

extern "C" void kernel_launch(void* const* d_in, const int* in_sizes, int n_in,
                              void* d_out, int out_size, void* d_ws, size_t ws_size,
                              hipStream_t stream) {
    const float* f0    = (const float*)d_in[0];
    const float* f1    = (const float*)d_in[1];
    const float* h0    = (const float*)d_in[2];
    const float* h1    = (const float*)d_in[3];
    const float* h2    = (const float*)d_in[4];
    const float* W_att = (const float*)d_in[5];
    const float* b_att = (const float*)d_in[6];
    const float* W_r1  = (const float*)d_in[7];
    const float* g_r1  = (const float*)d_in[8];
    const float* be_r1 = (const float*)d_in[9];
    const float* W_r2  = (const float*)d_in[10];
    const float* g_r2  = (const float*)d_in[11];
    const float* be_r2 = (const float*)d_in[12];
    const float* Wg0   = (const float*)d_in[13];
    const float* bg0   = (const float*)d_in[14];
    const float* Wc0   = (const float*)d_in[15];
    const float* Wg1   = (const float*)d_in[16];
    const float* bg1   = (const float*)d_in[17];
    const float* Wc1   = (const float*)d_in[18];

    float* out   = (float*)d_out;
    float* node0 = out;
    float* node1 = out + NPLANE;
    float* attO  = out + 2 * NPLANE;

    float* part1 = (float*)d_ws;              // 40*NB1 floats
    float* part2 = part1 + 40 * NB1;          // 20*NB2 floats
    int*   gate  = (int*)(part2 + 20 * NB2);  // 1 int

    kernA<<<dim3(NB1), dim3(256), 0, stream>>>(
        f0, f1, h0, h1, h2, W_att, b_att, W_r1, Wg0, bg0, Wc0,
        node0, attO, part1, gate);

    void* args[] = {
        (void*)&f1, (void*)&h1, (void*)&h2,
        (void*)&W_att, (void*)&b_att,
        (void*)&W_r1, (void*)&g_r1, (void*)&be_r1,
        (void*)&W_r2, (void*)&g_r2, (void*)&be_r2,
        (void*)&Wg1, (void*)&bg1, (void*)&Wc1,
        (void*)&part1, (void*)&part2, (void*)&gate,
        (void*)&node1
    };
    hipLaunchCooperativeKernel((const void*)kernBC, dim3(NB2), dim3(512),
                               args, 0, stream);
}

// Round 4
// 140.766 us; speedup vs baseline: 1.4952x; 1.2845x over previous
//
#include <hip/hip_runtime.h>
#include <math.h>

#define HW     16384
#define CDIM   10
#define NPIX   131072        // B*H*W
#define NPLANE 1310720       // B*C*H*W
#define BN_N   131072.0f
#define EPS_BN 1e-5f
#define NB     512           // blocks per kernel (256 thr each)

__device__ __forceinline__ float sigf(float x) { return 1.0f / (1.0f + __expf(-x)); }
__device__ __forceinline__ float tanh_fast(float x) {
    x = fminf(fmaxf(x, -15.0f), 15.0f);
    float e = __expf(2.0f * x);
    return (e - 1.0f) / (e + 1.0f);
}

// DPP-based 64-lane sum: VALU-only, no LDS/DS pipe. Result valid in lane 63.
template<int CTRL>
__device__ __forceinline__ float dpp_add(float x) {
    int t = __builtin_amdgcn_update_dpp(0, __float_as_int(x), CTRL, 0xF, 0xF, true);
    return x + __int_as_float(t);
}
__device__ __forceinline__ float wred63(float x) {
    x = dpp_add<0x111>(x);   // row_shr:1
    x = dpp_add<0x112>(x);   // row_shr:2
    x = dpp_add<0x114>(x);   // row_shr:4
    x = dpp_add<0x118>(x);   // row_shr:8
    x = dpp_add<0x142>(x);   // row_bcast:15
    x = dpp_add<0x143>(x);   // row_bcast:31 -> lane 63 = sum(0..63)
    return x;
}

// K A: node0 (GRU0), comp_att, BN1 partial stats -> part1[40][NB].
// No atomics, no memset: each block writes its own slot exactly once.
// Weights read from global with compile-time indices -> s_load/SGPR operands.
__global__ __launch_bounds__(256) void kernA(
    const float* __restrict__ f0, const float* __restrict__ f1,
    const float* __restrict__ h0, const float* __restrict__ h1, const float* __restrict__ h2,
    const float* __restrict__ W_att, const float* __restrict__ b_att,
    const float* __restrict__ W_r1,
    const float* __restrict__ Wg0, const float* __restrict__ bg0, const float* __restrict__ Wc0,
    float* __restrict__ node0, float* __restrict__ att_out, float* __restrict__ part1)
{
    __shared__ float sPart[4 * 40];
    const int tid = threadIdx.x;
    const int bid = blockIdx.x;
    const int p = bid * 256 + tid;
    const int b = p >> 14, s = p & 16383;
    const int base = b * (CDIM * HW) + s;
    const int wave = tid >> 6, lane = tid & 63;

    float vh1[10], vh2[10], vf1[10], vf0[10], vh0[10];
#pragma unroll
    for (int c = 0; c < 10; c++) {
        vh1[c] = h1[base + c * HW];
        vh2[c] = h2[base + c * HW];
        vf1[c] = f1[base + c * HW];
        vf0[c] = f0[base + c * HW];
        vh0[c] = h0[base + c * HW];
    }

    // node0 = GRU0(x=h0, h=f0)
    {
        float g0 = bg0[0], g1 = bg0[1];
#pragma unroll
        for (int i = 0; i < 10; i++) {
            g0 = fmaf(Wg0[i],      vh0[i], fmaf(Wg0[10 + i], vf0[i], g0));
            g1 = fmaf(Wg0[20 + i], vh0[i], fmaf(Wg0[30 + i], vf0[i], g1));
        }
        const float r = sigf(g0), u = sigf(g1);
#pragma unroll
        for (int o = 0; o < 10; o++) {
            float acc = 0.0f;
#pragma unroll
            for (int i = 0; i < 10; i++) acc = fmaf(Wc0[o * 20 + i], vh0[i], acc);
#pragma unroll
            for (int i = 0; i < 10; i++) acc = fmaf(Wc0[o * 20 + 10 + i], r * vf0[i], acc);
            node0[base + o * HW] = (1.0f - u) * vf0[o] + u * tanh_fast(acc);
        }
    }

    // comp_att
    float z = b_att[0];
#pragma unroll
    for (int c = 0; c < 10; c++) z = fmaf(W_att[c], vh1[c], fmaf(W_att[10 + c], vh2[c], z));
    const float att = sigf(z);
    att_out[p] = att;

    // x = [f1, (h1+h2)*att]; y1 = W_r1 @ x (stats only)
    float x[20];
#pragma unroll
    for (int c = 0; c < 10; c++) { x[c] = vf1[c]; x[10 + c] = (vh1[c] + vh2[c]) * att; }
#pragma unroll
    for (int o = 0; o < 20; o++) {
        float acc = 0.0f;
#pragma unroll
        for (int i = 0; i < 20; i++) acc = fmaf(W_r1[o * 20 + i], x[i], acc);
        float rs = wred63(acc);
        float rq = wred63(acc * acc);
        if (lane == 63) { sPart[wave * 40 + o] = rs; sPart[wave * 40 + 20 + o] = rq; }
    }
    __syncthreads();
    if (tid < 40) {
        float t = sPart[tid] + sPart[40 + tid] + sPart[80 + tid] + sPart[120 + tid];
        part1[tid * NB + bid] = t;   // layout [40][NB]
    }
}

// K C: reduce part1 per block (L2-resident), BN1 finalize, recompute att+y1,
// BN1+ReLU, y2 = W_r2 @ x2, BN2 partial stats -> part2[20][NB].
__global__ __launch_bounds__(256) void kernC(
    const float* __restrict__ f1, const float* __restrict__ h1, const float* __restrict__ h2,
    const float* __restrict__ W_att, const float* __restrict__ b_att,
    const float* __restrict__ W_r1, const float* __restrict__ g_r1, const float* __restrict__ be_r1,
    const float* __restrict__ W_r2,
    const float* __restrict__ part1, float* __restrict__ y2out, float* __restrict__ part2)
{
    __shared__ float sPart[4 * 20];
    __shared__ float sRed[40];
    const int tid = threadIdx.x;
    const int bid = blockIdx.x;
    const int p = bid * 256 + tid;
    const int b = p >> 14, s = p & 16383;
    const int base = b * (CDIM * HW) + s;
    const int wave = tid >> 6, lane = tid & 63;

    // redundant per-block reduction of part1[40][NB]
    for (int ch = wave; ch < 40; ch += 4) {
        float v = 0.0f;
#pragma unroll
        for (int k = 0; k < 8; k++) v += part1[ch * NB + k * 64 + lane];
        v = wred63(v);
        if (lane == 63) sRed[ch] = v;
    }
    __syncthreads();
    float A1[20], B1[20];
#pragma unroll
    for (int c = 0; c < 20; c++) {
        float mean = sRed[c] * (1.0f / BN_N);
        float var  = sRed[20 + c] * (1.0f / BN_N) - mean * mean;
        float a = g_r1[c] * rsqrtf(var + EPS_BN);
        A1[c] = a;
        B1[c] = be_r1[c] - mean * a;
    }

    float vh1[10], vh2[10], vf1[10];
#pragma unroll
    for (int c = 0; c < 10; c++) {
        vh1[c] = h1[base + c * HW];
        vh2[c] = h2[base + c * HW];
        vf1[c] = f1[base + c * HW];
    }
    float z = b_att[0];
#pragma unroll
    for (int c = 0; c < 10; c++) z = fmaf(W_att[c], vh1[c], fmaf(W_att[10 + c], vh2[c], z));
    const float att = sigf(z);

    float x[20];
#pragma unroll
    for (int c = 0; c < 10; c++) { x[c] = vf1[c]; x[10 + c] = (vh1[c] + vh2[c]) * att; }
    float x2[20];
#pragma unroll
    for (int o = 0; o < 20; o++) {
        float acc = 0.0f;
#pragma unroll
        for (int i = 0; i < 20; i++) acc = fmaf(W_r1[o * 20 + i], x[i], acc);
        x2[o] = fmaxf(fmaf(A1[o], acc, B1[o]), 0.0f);
    }
    const int base2 = b * (10 * HW) + s;
#pragma unroll
    for (int o = 0; o < 10; o++) {
        float acc = 0.0f;
#pragma unroll
        for (int i = 0; i < 20; i++) acc = fmaf(W_r2[o * 20 + i], x2[i], acc);
        y2out[base2 + o * HW] = acc;
        float rs = wred63(acc);
        float rq = wred63(acc * acc);
        if (lane == 63) { sPart[wave * 20 + o] = rs; sPart[wave * 20 + 10 + o] = rq; }
    }
    __syncthreads();
    if (tid < 20) {
        float t = sPart[tid] + sPart[20 + tid] + sPart[40 + tid] + sPart[60 + tid];
        part2[tid * NB + bid] = t;   // layout [20][NB]
    }
}

// K E: reduce part2 per block, BN2 finalize, comp_full = ReLU(BN2(y2)),
// node1 = GRU1(comp_full, f1).
__global__ __launch_bounds__(256) void kernE(
    const float* __restrict__ f1, const float* __restrict__ y2in,
    const float* __restrict__ part2,
    const float* __restrict__ g_r2, const float* __restrict__ be_r2,
    const float* __restrict__ Wg1, const float* __restrict__ bg1, const float* __restrict__ Wc1,
    float* __restrict__ node1)
{
    __shared__ float sRed[20];
    const int tid = threadIdx.x;
    const int bid = blockIdx.x;
    const int p = bid * 256 + tid;
    const int b = p >> 14, s = p & 16383;
    const int base = b * (CDIM * HW) + s;
    const int wave = tid >> 6, lane = tid & 63;

    for (int ch = wave; ch < 20; ch += 4) {
        float v = 0.0f;
#pragma unroll
        for (int k = 0; k < 8; k++) v += part2[ch * NB + k * 64 + lane];
        v = wred63(v);
        if (lane == 63) sRed[ch] = v;
    }
    __syncthreads();

    float A2[10], B2[10];
#pragma unroll
    for (int c = 0; c < 10; c++) {
        float mean = sRed[c] * (1.0f / BN_N);
        float var  = sRed[10 + c] * (1.0f / BN_N) - mean * mean;
        float a = g_r2[c] * rsqrtf(var + EPS_BN);
        A2[c] = a;
        B2[c] = be_r2[c] - mean * a;
    }

    float comp[10], vf1[10];
#pragma unroll
    for (int c = 0; c < 10; c++) {
        vf1[c]  = f1[base + c * HW];
        comp[c] = fmaxf(fmaf(A2[c], y2in[base + c * HW], B2[c]), 0.0f);
    }
    float g0 = bg1[0], g1v = bg1[1];
#pragma unroll
    for (int i = 0; i < 10; i++) {
        g0  = fmaf(Wg1[i],      comp[i], fmaf(Wg1[10 + i], vf1[i], g0));
        g1v = fmaf(Wg1[20 + i], comp[i], fmaf(Wg1[30 + i], vf1[i], g1v));
    }
    const float r = sigf(g0), u = sigf(g1v);
#pragma unroll
    for (int o = 0; o < 10; o++) {
        float acc = 0.0f;
#pragma unroll
        for (int i = 0; i < 10; i++) acc = fmaf(Wc1[o * 20 + i], comp[i], acc);
#pragma unroll
        for (int i = 0; i < 10; i++) acc = fmaf(Wc1[o * 20 + 10 + i], r * vf1[i], acc);
        node1[base + o * HW] = (1.0f - u) * vf1[o] + u * tanh_fast(acc);
    }
}

extern "C" void kernel_launch(void* const* d_in, const int* in_sizes, int n_in,
                              void* d_out, int out_size, void* d_ws, size_t ws_size,
                              hipStream_t stream) {
    const float* f0    = (const float*)d_in[0];
    const float* f1    = (const float*)d_in[1];
    const float* h0    = (const float*)d_in[2];
    const float* h1    = (const float*)d_in[3];
    const float* h2    = (const float*)d_in[4];
    const float* W_att = (const float*)d_in[5];
    const float* b_att = (const float*)d_in[6];
    const float* W_r1  = (const float*)d_in[7];
    const float* g_r1  = (const float*)d_in[8];
    const float* be_r1 = (const float*)d_in[9];
    const float* W_r2  = (const float*)d_in[10];
    const float* g_r2  = (const float*)d_in[11];
    const float* be_r2 = (const float*)d_in[12];
    const float* Wg0   = (const float*)d_in[13];
    const float* bg0   = (const float*)d_in[14];
    const float* Wc0   = (const float*)d_in[15];
    const float* Wg1   = (const float*)d_in[16];
    const float* bg1   = (const float*)d_in[17];
    const float* Wc1   = (const float*)d_in[18];

    float* out   = (float*)d_out;
    float* node0 = out;
    float* node1 = out + NPLANE;
    float* attO  = out + 2 * NPLANE;

    float* y2    = (float*)d_ws;              // NPIX*10 floats
    float* part1 = y2 + (size_t)10 * NPIX;    // 40*NB floats
    float* part2 = part1 + 40 * NB;           // 20*NB floats

    dim3 grid(NB), blk(256);
    kernA<<<grid, blk, 0, stream>>>(f0, f1, h0, h1, h2, W_att, b_att, W_r1,
                                    Wg0, bg0, Wc0, node0, attO, part1);
    kernC<<<grid, blk, 0, stream>>>(f1, h1, h2, W_att, b_att, W_r1, g_r1, be_r1,
                                    W_r2, part1, y2, part2);
    kernE<<<grid, blk, 0, stream>>>(f1, y2, part2, g_r2, be_r2, Wg1, bg1, Wc1,
                                    node1);
}